// Round 8
// baseline (1383.689 us; speedup 1.0000x reference)
//
#include <hip/hip_runtime.h>
#include <cstdint>
#include <cstddef>

#define BB 64
#define NN 512
#define DD 768
#define KB 64
#define NSTEP (NN/KB)

typedef __bf16 bf16x8 __attribute__((ext_vector_type(8)));
typedef float f32x4 __attribute__((ext_vector_type(4)));
typedef unsigned short us8 __attribute__((ext_vector_type(8)));
typedef double f64x4 __attribute__((ext_vector_type(4)));
typedef double f64x2 __attribute__((ext_vector_type(2)));

__device__ __forceinline__ float aval(float adjv, float mi, float mj) {
    return expf(fmaxf(adjv - 50.f * (mi + mj), -40.f));
}

__device__ __forceinline__ unsigned short f2bf(float v) {
    union { float f; unsigned int u; } c; c.f = v;
    return (unsigned short)((c.u + 0x7fffu + ((c.u >> 16) & 1u)) >> 16);
}
__device__ __forceinline__ float bf2f(unsigned short h) {
    union { unsigned int u; float f; } c; c.u = ((unsigned int)h) << 16;
    return c.f;
}

__device__ __forceinline__ void gl_lds16(const void* g, void* l) {
    __builtin_amdgcn_global_load_lds((const __attribute__((address_space(1))) unsigned int*)g,
                                     (__attribute__((address_space(3))) unsigned int*)l, 16, 0, 0);
}

// ---------------- root / R ----------------
__global__ void k_root(const float* __restrict__ x, const float* __restrict__ mask,
                       const float* __restrict__ w, const float* __restrict__ br,
                       float* __restrict__ R) {
    int wave = threadIdx.x >> 6, lane = threadIdx.x & 63;
    int row = blockIdx.x * 4 + wave;
    const float* xr = x + (size_t)row * DD;
    float s = 0.f;
#pragma unroll
    for (int k = 0; k < DD / 64; ++k) s += xr[k * 64 + lane] * w[k * 64 + lane];
    for (int off = 32; off; off >>= 1) s += __shfl_down(s, off, 64);
    if (lane == 0) {
        float m = mask[row] * -1e-4f;
        float rv = fmaxf(s + br[0] - 50.f * m, -40.f);
        R[row] = expf(rv);
    }
}

// ---------------- column sums of A (partials) ----------------
__global__ void k_colsum(const float* __restrict__ adj, const float* __restrict__ mask,
                         double* __restrict__ Lp) {
    int b = blockIdx.x, chunk = blockIdx.y;
    int j = threadIdx.x;
    float mj = mask[b * NN + j] * -1e-4f;
    const float* ab = adj + (size_t)b * NN * NN;
    double acc = 0.0;
    int i0 = chunk * 128;
    for (int i = i0; i < i0 + 128; ++i) {
        float mi = mask[b * NN + i] * -1e-4f;
        acc += (double)aval(ab[(size_t)i * NN + j], mi, mj);
    }
    Lp[((size_t)b * 4 + chunk) * NN + j] = acc;
}

// ---------------- build LL ----------------
template <typename T>
__global__ void k_build(const float* __restrict__ adj, const float* __restrict__ mask,
                        const float* __restrict__ R, const double* __restrict__ Lp,
                        T* __restrict__ M) {
    int b = blockIdx.x >> 9;
    int r = blockIdx.x & 511;
    int c = threadIdx.x;
    float mr = mask[b * NN + r] * -1e-4f;
    float mc = mask[b * NN + c] * -1e-4f;
    size_t idx = ((size_t)b * NN + r) * NN + c;
    float a = aval(adj[idx], mr, mc);
    T v;
    if (r == c) {
        const double* lp = Lp + (size_t)b * 4 * NN;
        double L = lp[c] + lp[NN + c] + lp[2 * NN + c] + lp[3 * NN + c];
        v = (T)(L - (double)a + (double)R[b * NN + c]);
    } else {
        v = (T)(-a);
    }
    M[idx] = v;
}

// ---------------- save column panel (fallback path only) ----------------
template <typename T>
__global__ void k_savecol(const T* __restrict__ M, T* __restrict__ Cb, int k0) {
    int t = threadIdx.x;
    int c = t & 63, rr = t >> 6;
    int row = blockIdx.x * 4 + rr;
    int b = row >> 9, i = row & 511;
    Cb[(size_t)row * KB + c] = M[((size_t)b * NN + i) * NN + k0 + c];
}

// ---------------- invert 64x64 pivot block (fallback path only) ----------------
template <typename T>
__global__ void k_invblk(const T* __restrict__ M, T* __restrict__ Bb, int k0) {
    __shared__ double pr[KB];
    __shared__ double fv[KB];
    __shared__ double pvt;
    int b = blockIdx.x;
    int r = threadIdx.x & 63, q = threadIdx.x >> 6;
    double a[16];
    const T* Mb = M + ((size_t)b * NN + k0) * NN + k0;
#pragma unroll
    for (int c = 0; c < 16; ++c) a[c] = (double)Mb[(size_t)r * NN + q * 16 + c];
    for (int k = 0; k < KB; ++k) {
        int kq = k >> 4, kc = k & 15;
        if (r == k && q == kq) pvt = a[kc];
        __syncthreads();
        double ip = 1.0 / pvt;
        if (r == k) {
#pragma unroll
            for (int c = 0; c < 16; ++c) a[c] *= ip;
            if (q == kq) a[kc] = ip;
#pragma unroll
            for (int c = 0; c < 16; ++c) pr[q * 16 + c] = a[c];
        }
        if (r != k && q == kq) fv[r] = a[kc];
        __syncthreads();
        if (r != k) {
            double f = fv[r];
#pragma unroll
            for (int c = 0; c < 16; ++c) a[c] -= f * pr[q * 16 + c];
            if (q == kq) a[kc] = -f * ip;
        }
        __syncthreads();
    }
    T* Bo = Bb + (size_t)b * KB * KB;
#pragma unroll
    for (int c = 0; c < 16; ++c) Bo[r * KB + q * 16 + c] = (T)a[c];
}

// ---------------- fused inversion + pivot rows ----------------
// Every block redundantly inverts M[step][step] (read from previous kernel's
// writes - stream-ordered, no cross-block deps). jt==step block publishes
// Bb + pivot diag; others compute R(step,jt) = Binv @ Mold via MFMA.
// f64 16x16x4 C/D map (HW-verified r4/r5): row = (lane>>4) + 4*reg, col = lane&15
__global__ __launch_bounds__(256) void k_piv2(double* __restrict__ M,
                                              double* __restrict__ Bb, int step) {
    __shared__ double Ms[64][66];
    __shared__ double Bs[64][66];
    __shared__ double pr[KB];
    __shared__ double fv[KB];
    __shared__ double pvt;
    int b = blockIdx.y, jt = blockIdx.x;
    int t = threadIdx.x, w = t >> 6, l = t & 63;
    double* Mb = M + (size_t)b * NN * NN;
    double* Pr = Mb + (size_t)(step * 64) * NN;
    // stage Mold(step, jt) early (loads overlap the inversion's latency)
    if (jt != step) {
        const double* Mg = Pr + jt * 64;
        for (int i = 0; i < 8; ++i) {
            int c = i * 256 + t;
            int row = c >> 5, ch = c & 31;
            f64x2 v = *(const f64x2*)(Mg + (size_t)row * NN + ch * 2);
            Ms[row][ch * 2] = v[0]; Ms[row][ch * 2 + 1] = v[1];
        }
    }
    // redundant 64x64 GJ inversion of M[step][step]
    {
        int r = t & 63, q = t >> 6;
        double a[16];
        const double* Pp = Pr + step * 64;
#pragma unroll
        for (int c = 0; c < 16; ++c) a[c] = Pp[(size_t)r * NN + q * 16 + c];
        for (int k = 0; k < KB; ++k) {
            int kq = k >> 4, kc = k & 15;
            if (r == k && q == kq) pvt = a[kc];
            __syncthreads();
            double ip = 1.0 / pvt;
            if (r == k) {
#pragma unroll
                for (int c = 0; c < 16; ++c) a[c] *= ip;
                if (q == kq) a[kc] = ip;
#pragma unroll
                for (int c = 0; c < 16; ++c) pr[q * 16 + c] = a[c];
            }
            if (r != k && q == kq) fv[r] = a[kc];
            __syncthreads();
            if (r != k) {
                double f = fv[r];
#pragma unroll
                for (int c = 0; c < 16; ++c) a[c] -= f * pr[q * 16 + c];
                if (q == kq) a[kc] = -f * ip;
            }
            __syncthreads();
        }
#pragma unroll
        for (int c = 0; c < 16; ++c) Bs[r][q * 16 + c] = a[c];
        if (jt == step) {
            double* Bo = Bb + (size_t)b * KB * KB;
#pragma unroll
            for (int c = 0; c < 16; ++c) {
                Bo[r * KB + q * 16 + c] = a[c];
                Pr[(size_t)r * NN + step * 64 + q * 16 + c] = a[c];
            }
            return;
        }
    }
    __syncthreads();
    int lr = l & 15, lg = l >> 4;
    double af[16];
#pragma unroll
    for (int kk = 0; kk < 16; ++kk) af[kk] = Bs[w * 16 + lr][kk * 4 + lg];
    double* Og = Pr + (size_t)(w * 16) * NN + jt * 64;
#pragma unroll
    for (int cf = 0; cf < 4; ++cf) {
        f64x4 acc = {0., 0., 0., 0.};
#pragma unroll
        for (int kk = 0; kk < 16; ++kk)
            acc = __builtin_amdgcn_mfma_f64_16x16x4f64(af[kk], Ms[kk * 4 + lg][cf * 16 + lr], acc, 0, 0, 0);
#pragma unroll
        for (int r2 = 0; r2 < 4; ++r2) Og[(size_t)(lg + 4 * r2) * NN + cf * 16 + lr] = acc[r2];
    }
}

// ---------------- fused MFMA rank-64 update (upd0 + upd1) ----------------
__global__ __launch_bounds__(256) void k_upd2(double* __restrict__ M,
                                              const double* __restrict__ Bb, int step) {
    __shared__ double Ts[64][66];
    int b = blockIdx.y;
    int x = blockIdx.x;
    int it = x >> 1, half = x & 1;
    if (it >= step) ++it;
    int t = threadIdx.x, w = t >> 6, l = t & 63;
    double* Mb = M + (size_t)b * NN * NN;
    {
        const double* Cg = Mb + (size_t)(it * 64) * NN + step * 64;
        for (int i = 0; i < 8; ++i) {
            int c = i * 256 + t;
            int row = c >> 5, ch = c & 31;
            f64x2 v = *(const f64x2*)(Cg + (size_t)row * NN + ch * 2);
            Ts[row][ch * 2] = -v[0]; Ts[row][ch * 2 + 1] = -v[1];
        }
    }
    __syncthreads();
    int lr = l & 15, lg = l >> 4;
    double a[16];
#pragma unroll
    for (int kk = 0; kk < 16; ++kk) a[kk] = Ts[w * 16 + lr][kk * 4 + lg];
    __syncthreads();
    int nj = half ? 3 : 4;
    for (int jj = 0; jj < nj; ++jj) {
        int jtidx = half ? 4 + jj : jj;
        int jt = (jtidx < step) ? jtidx : jtidx + 1;
        const double* Rg = Mb + (size_t)(step * 64) * NN + jt * 64;
        for (int i = 0; i < 8; ++i) {
            int c = i * 256 + t;
            int row = c >> 5, ch = c & 31;
            f64x2 v = *(const f64x2*)(Rg + (size_t)row * NN + ch * 2);
            Ts[row][ch * 2] = v[0]; Ts[row][ch * 2 + 1] = v[1];
        }
        __syncthreads();
        double* Og = Mb + (size_t)(it * 64 + w * 16) * NN + jt * 64;
#pragma unroll
        for (int cf = 0; cf < 4; ++cf) {
            int c0 = cf * 16 + lr;
            f64x4 acc;
#pragma unroll
            for (int r = 0; r < 4; ++r) acc[r] = Og[(size_t)(lg + 4 * r) * NN + c0];
#pragma unroll
            for (int kk = 0; kk < 16; ++kk)
                acc = __builtin_amdgcn_mfma_f64_16x16x4f64(a[kk], Ts[kk * 4 + lg][c0], acc, 0, 0, 0);
#pragma unroll
            for (int r = 0; r < 4; ++r) Og[(size_t)(lg + 4 * r) * NN + c0] = acc[r];
        }
        __syncthreads();
    }
    if (half) {
        const double* Bi = Bb + (size_t)b * KB * KB;
        for (int i = 0; i < 8; ++i) {
            int c = i * 256 + t;
            int row = c >> 5, ch = c & 31;
            f64x2 v = *(const f64x2*)(Bi + row * 64 + ch * 2);
            Ts[row][ch * 2] = v[0]; Ts[row][ch * 2 + 1] = v[1];
        }
        __syncthreads();
        double* Og = Mb + (size_t)(it * 64 + w * 16) * NN + step * 64;
#pragma unroll
        for (int cf = 0; cf < 4; ++cf) {
            int c0 = cf * 16 + lr;
            f64x4 acc = {0., 0., 0., 0.};
#pragma unroll
            for (int kk = 0; kk < 16; ++kk)
                acc = __builtin_amdgcn_mfma_f64_16x16x4f64(a[kk], Ts[kk * 4 + lg][c0], acc, 0, 0, 0);
#pragma unroll
            for (int r = 0; r < 4; ++r) Og[(size_t)(lg + 4 * r) * NN + c0] = acc[r];
        }
    }
}

// ---------------- scalar pivrows / update (fallback path only) ----------------
template <typename T>
__global__ void k_pivrows(T* __restrict__ M, const T* __restrict__ Bb, int k0) {
    __shared__ double Bi[KB][KB];
    __shared__ double Mt[KB][KB + 1];
    int b = blockIdx.x, jt = blockIdx.y * 64;
    const T* Bo = Bb + (size_t)b * KB * KB;
    T* Mb = M + ((size_t)b * NN + k0) * NN;
    int t = threadIdx.x;
    for (int e = t; e < KB * KB; e += 256) {
        int rr = e >> 6, cc = e & 63;
        Bi[rr][cc] = (double)Bo[e];
        Mt[rr][cc] = (double)Mb[(size_t)rr * NN + jt + cc];
    }
    __syncthreads();
    if (blockIdx.y == (unsigned)(k0 >> 6)) {
        for (int e = t; e < KB * KB; e += 256) {
            int rr = e >> 6, cc = e & 63;
            Mb[(size_t)rr * NN + jt + cc] = (T)Bi[rr][cc];
        }
        return;
    }
    int tx = t & 15, ty = t >> 4;
    double acc[4][4] = {};
    for (int k = 0; k < KB; ++k) {
        double av[4], bv[4];
#pragma unroll
        for (int u = 0; u < 4; ++u) { av[u] = Bi[ty * 4 + u][k]; bv[u] = Mt[k][tx * 4 + u]; }
#pragma unroll
        for (int u = 0; u < 4; ++u)
#pragma unroll
            for (int v = 0; v < 4; ++v) acc[u][v] += av[u] * bv[v];
    }
#pragma unroll
    for (int u = 0; u < 4; ++u)
#pragma unroll
        for (int v = 0; v < 4; ++v)
            Mb[(size_t)(ty * 4 + u) * NN + jt + tx * 4 + v] = (T)acc[u][v];
}

template <typename T>
__global__ void k_update(T* __restrict__ M, const T* __restrict__ Cb, int k0) {
    int step = k0 >> 6;
    int it = blockIdx.y;
    if (it == step) return;
    int b = blockIdx.x, jt = blockIdx.z;
    __shared__ double Ct[KB][KB + 1];
    __shared__ double Rt[KB][KB + 1];
    int t = threadIdx.x;
    const T* Cbb = Cb + ((size_t)b * NN + it * 64) * KB;
    const T* Rb  = M + ((size_t)b * NN + k0) * NN + jt * 64;
    for (int e = t; e < KB * KB; e += 256) {
        int rr = e >> 6, cc = e & 63;
        Ct[rr][cc] = (double)Cbb[(size_t)rr * KB + cc];
        Rt[rr][cc] = (double)Rb[(size_t)rr * NN + cc];
    }
    __syncthreads();
    int tx = t & 15, ty = t >> 4;
    double acc[4][4] = {};
    for (int k = 0; k < KB; ++k) {
        double av[4], bv[4];
#pragma unroll
        for (int u = 0; u < 4; ++u) { av[u] = Ct[ty * 4 + u][k]; bv[u] = Rt[k][tx * 4 + u]; }
#pragma unroll
        for (int u = 0; u < 4; ++u)
#pragma unroll
            for (int v = 0; v < 4; ++v) acc[u][v] += av[u] * bv[v];
    }
    T* Mo = M + ((size_t)b * NN + it * 64) * NN + jt * 64;
    bool blockcol = (jt == step);
#pragma unroll
    for (int u = 0; u < 4; ++u) {
        int row = ty * 4 + u;
#pragma unroll
        for (int v = 0; v < 4; ++v) {
            int col = tx * 4 + v;
            double val = (double)Mo[(size_t)row * NN + col] - acc[u][v];
            if (blockcol) val -= Ct[row][col];
            Mo[(size_t)row * NN + col] = (T)val;
        }
    }
}

// ---------------- diag extraction + BCE loss ----------------
template <typename T>
__global__ void k_dgloss(const T* __restrict__ M, const float* __restrict__ R,
                         const float* __restrict__ rlab, const int* __restrict__ rmask,
                         double* __restrict__ Dg, float* __restrict__ lossp) {
    int idx = blockIdx.x * 256 + threadIdx.x;
    int b = idx >> 9, n = idx & 511;
    double xv = (double)M[((size_t)b * NN + n) * NN + n];
    Dg[idx] = xv;
    float d0 = R[idx] * (float)xv;
    float lg = fminf(fmaxf(d0, 1e-5f), 1.f - 1e-5f);
    float rm = (float)rmask[idx];
    float lab = (rmask[idx] == 1) ? rlab[idx] : 0.f;
    float bce = -(lab * logf(lg) + (1.f - lab) * logf(1.f - lg));
    __shared__ double sm[256];
    sm[threadIdx.x] = (double)(bce * rm);
    __syncthreads();
    for (int s = 128; s; s >>= 1) {
        if (threadIdx.x < s) sm[threadIdx.x] += sm[threadIdx.x + s];
        __syncthreads();
    }
    if (threadIdx.x == 0) lossp[blockIdx.x] = (float)sm[0];
}

__global__ void k_lossfin(const float* __restrict__ lossp, float* __restrict__ outv) {
    __shared__ double sm[128];
    sm[threadIdx.x] = (double)lossp[threadIdx.x];
    __syncthreads();
    for (int s = 64; s; s >>= 1) {
        if (threadIdx.x < s) sm[threadIdx.x] += sm[threadIdx.x + s];
        __syncthreads();
    }
    if (threadIdx.x == 0) outv[0] = (float)(sm[0] / (double)(BB * NN));
}

// ---------------- d (fallback path) ----------------
template <typename T>
__global__ void k_d(const T* __restrict__ M, const double* __restrict__ Dg,
                    const float* __restrict__ adj, const float* __restrict__ mask,
                    float* __restrict__ dout) {
    int b = blockIdx.x, i0 = blockIdx.y * 64, j0 = blockIdx.z * 64;
    __shared__ double Xt[64][65];
    int t = threadIdx.x, ii = t & 63, jj0 = t >> 6;
    const T* Mb = M + (size_t)b * NN * NN;
    for (int jj = jj0; jj < 64; jj += 4)
        Xt[jj][ii] = (double)Mb[(size_t)(j0 + jj) * NN + i0 + ii];
    __syncthreads();
    int jc = t & 63, ir0 = t >> 6;
    float mj = mask[b * NN + j0 + jc] * -1e-4f;
    double dg = Dg[b * NN + j0 + jc];
    const float* ab = adj + (size_t)b * NN * NN;
    float* db = dout + (size_t)b * NN * NN;
    for (int ir = ir0; ir < 64; ir += 4) {
        int i = i0 + ir;
        float mi = mask[b * NN + i] * -1e-4f;
        float a = aval(ab[(size_t)i * NN + j0 + jc], mi, mj);
        db[(size_t)i * NN + j0 + jc] = a * (float)(dg - Xt[jc][ir]);
    }
}

// ---------------- d + transposed masked bf16 hi/lo attn (f32 X staging) ----------------
template <typename T>
__global__ void k_d2(const T* __restrict__ M, const double* __restrict__ Dg,
                     const float* __restrict__ adj, const float* __restrict__ mask,
                     float* __restrict__ dout,
                     unsigned short* __restrict__ ATh, unsigned short* __restrict__ ATl) {
    int b = blockIdx.x, i0 = blockIdx.y * 64, j0 = blockIdx.z * 64;
    __shared__ float Xt[64][65];
    __shared__ float dt[64][65];
    int t = threadIdx.x, ii = t & 63, jj0 = t >> 6;
    const T* Mb = M + (size_t)b * NN * NN;
    for (int jj = jj0; jj < 64; jj += 4)
        Xt[jj][ii] = (float)Mb[(size_t)(j0 + jj) * NN + i0 + ii];
    __syncthreads();
    int jc = t & 63, ir0 = t >> 6;
    float mj = mask[b * NN + j0 + jc] * -1e-4f;
    double dg = Dg[b * NN + j0 + jc];
    const float* ab = adj + (size_t)b * NN * NN;
    float* db = dout + (size_t)b * NN * NN;
    for (int ir = ir0; ir < 64; ir += 4) {
        int i = i0 + ir;
        float mi = mask[b * NN + i] * -1e-4f;
        float a = aval(ab[(size_t)i * NN + j0 + jc], mi, mj);
        float v = a * (float)(dg - (double)Xt[jc][ir]);
        db[(size_t)i * NN + j0 + jc] = v;
        dt[ir][jc] = v;
    }
    __syncthreads();
    int ql = t >> 2, kq = t & 3;
    us8 vh0, vh1, vl0, vl1;
#pragma unroll
    for (int u = 0; u < 16; ++u) {
        int k = kq * 16 + u;
        float mk = mask[b * NN + i0 + k] * -1e-4f;
        float v = (mk > 0.5f) ? 0.f : dt[k][ql];
        unsigned short h = f2bf(v);
        unsigned short lo = f2bf(v - bf2f(h));
        if (u < 8) { vh0[u] = h; vl0[u] = lo; } else { vh1[u - 8] = h; vl1[u - 8] = lo; }
    }
    size_t ao = ((size_t)b * NN + j0 + ql) * NN + i0 + kq * 16;
    *(us8*)&ATh[ao] = vh0; *(us8*)&ATh[ao + 8] = vh1;
    *(us8*)&ATl[ao] = vl0; *(us8*)&ATl[ao + 8] = vl1;
}

// ---------------- x -> transposed bf16 hi/lo ----------------
__global__ void k_cvt_x(const float* __restrict__ x,
                        unsigned short* __restrict__ XTh, unsigned short* __restrict__ XTl) {
    int b = blockIdx.x, k0 = blockIdx.y * 64, c0 = blockIdx.z * 64;
    __shared__ float xs[64][65];
    int t = threadIdx.x;
#pragma unroll
    for (int rep = 0; rep < 16; ++rep) {
        int e = rep * 256 + t;
        int row = e >> 6, col = e & 63;
        xs[row][col] = x[((size_t)b * NN + k0 + row) * DD + c0 + col];
    }
    __syncthreads();
    int cl = t >> 2, kq = t & 3;
    us8 vh0, vh1, vl0, vl1;
#pragma unroll
    for (int u = 0; u < 16; ++u) {
        int k = kq * 16 + u;
        float v = xs[k][cl];
        unsigned short h = f2bf(v);
        unsigned short lo = f2bf(v - bf2f(h));
        if (u < 8) { vh0[u] = h; vl0[u] = lo; } else { vh1[u - 8] = h; vl1[u - 8] = lo; }
    }
    size_t ao = ((size_t)b * DD + c0 + cl) * NN + k0 + kq * 16;
    *(us8*)&XTh[ao] = vh0; *(us8*)&XTh[ao + 8] = vh1;
    *(us8*)&XTl[ao] = vl0; *(us8*)&XTl[ao + 8] = vl1;
}

// ---------------- context GEMM: fused single-pass, double-buffered ----------------
// T3-min: prefetch K-tile kt+1 into buf^1, counted vmcnt(8) + raw s_barrier.
// Grid (bn, bm, b) with bn fastest => blocks sharing the A panel are linear-
// adjacent => XCD-local L2 reuse (T1).
__global__ __launch_bounds__(256) void k_ctx4(const unsigned short* __restrict__ ATh,
                                              const unsigned short* __restrict__ ATl,
                                              const unsigned short* __restrict__ XTh,
                                              const unsigned short* __restrict__ XTl,
                                              float* __restrict__ ctx) {
    __shared__ __align__(16) unsigned short ABs[2][128 * 64];
    __shared__ __align__(16) unsigned short Xs[2][128 * 64];
    int b = blockIdx.z;
    int bm = blockIdx.y * 128, bn = blockIdx.x * 128;
    int t = threadIdx.x, wid = t >> 6, lane = t & 63;
    f32x4 acc[4][4];
#pragma unroll
    for (int i = 0; i < 4; ++i)
#pragma unroll
        for (int j = 0; j < 4; ++j) acc[i][j] = (f32x4){0.f, 0.f, 0.f, 0.f};

    const unsigned short* Agh = ATh + ((size_t)b * NN + bm) * NN;
    const unsigned short* Agl = ATl + ((size_t)b * NN + bm) * NN;
    const unsigned short* Xgh = XTh + ((size_t)b * DD + bn) * NN;
    const unsigned short* Xgl = XTl + ((size_t)b * DD + bn) * NN;

    int m0 = (wid >> 1) * 64, n0 = (wid & 1) * 64;
    int kc = lane >> 4;

    auto STAGE = [&](int kt, int buf) {
        int ki = kt * 32;
#pragma unroll
        for (int it2 = 0; it2 < 4; ++it2) {
            int chunk = it2 * 256 + wid * 64 + lane;
            int row = chunk >> 3;
            int gs = (chunk & 7) ^ (row & 7);
            const unsigned short* s = (gs < 4) ? Agh + (size_t)row * NN + ki + gs * 8
                                               : Agl + (size_t)row * NN + ki + (gs - 4) * 8;
            gl_lds16(s, &ABs[buf][(it2 * 256 + wid * 64) * 8]);
        }
#pragma unroll
        for (int it2 = 0; it2 < 4; ++it2) {
            int chunk = it2 * 256 + wid * 64 + lane;
            int row = chunk >> 3;
            int gs = (chunk & 7) ^ (row & 7);
            const unsigned short* s = (gs < 4) ? Xgh + (size_t)row * NN + ki + gs * 8
                                               : Xgl + (size_t)row * NN + ki + (gs - 4) * 8;
            gl_lds16(s, &Xs[buf][(it2 * 256 + wid * 64) * 8]);
        }
    };

    STAGE(0, 0);
    int cur = 0;
    for (int kt = 0; kt < 16; ++kt) {
        if (kt + 1 < 16) {
            STAGE(kt + 1, cur ^ 1);
            asm volatile("s_waitcnt vmcnt(8)" ::: "memory");
        } else {
            asm volatile("s_waitcnt vmcnt(0)" ::: "memory");
        }
        __builtin_amdgcn_s_barrier();
        bf16x8 ah[4], al[4], xh[4], xl[4];
#pragma unroll
        for (int f = 0; f < 4; ++f) {
            int ar = m0 + f * 16 + (lane & 15);
            ah[f] = *(const bf16x8*)&ABs[cur][(ar * 8 + (kc ^ (ar & 7))) * 8];
            al[f] = *(const bf16x8*)&ABs[cur][(ar * 8 + ((kc | 4) ^ (ar & 7))) * 8];
            int br = n0 + f * 16 + (lane & 15);
            xh[f] = *(const bf16x8*)&Xs[cur][(br * 8 + (kc ^ (br & 7))) * 8];
            xl[f] = *(const bf16x8*)&Xs[cur][(br * 8 + ((kc | 4) ^ (br & 7))) * 8];
        }
#pragma unroll
        for (int fm = 0; fm < 4; ++fm)
#pragma unroll
            for (int fn = 0; fn < 4; ++fn) {
                acc[fm][fn] = __builtin_amdgcn_mfma_f32_16x16x32_bf16(ah[fm], xh[fn], acc[fm][fn], 0, 0, 0);
                acc[fm][fn] = __builtin_amdgcn_mfma_f32_16x16x32_bf16(ah[fm], xl[fn], acc[fm][fn], 0, 0, 0);
                acc[fm][fn] = __builtin_amdgcn_mfma_f32_16x16x32_bf16(al[fm], xh[fn], acc[fm][fn], 0, 0, 0);
            }
        __builtin_amdgcn_s_barrier();
        cur ^= 1;
    }
    float* cb = ctx + ((size_t)b * NN + bm + m0) * DD + bn + n0;
#pragma unroll
    for (int fm = 0; fm < 4; ++fm)
#pragma unroll
        for (int fn = 0; fn < 4; ++fn)
#pragma unroll
            for (int r = 0; r < 4; ++r) {
                int row = fm * 16 + (lane >> 4) * 4 + r;
                int col = fn * 16 + (lane & 15);
                cb[(size_t)row * DD + col] = acc[fm][fn][r];
            }
}

// ---------------- context (fallback) ----------------
__global__ void k_ctx(const float* __restrict__ dmat, const float* __restrict__ x,
                      const float* __restrict__ mask, float* __restrict__ ctx) {
    int b = blockIdx.x, i0 = blockIdx.y * 64, c0 = blockIdx.z * 64;
    __shared__ float At[32][65];
    __shared__ float Xl[32][65];
    int t = threadIdx.x;
    int tx = t & 15, ty = t >> 4;
    float acc[4][4] = {};
    const float* db = dmat + (size_t)b * NN * NN;
    const float* xb = x + (size_t)b * NN * DD;
    int li = t & 63, lk = t >> 6;
    for (int kt = 0; kt < NN; kt += 32) {
#pragma unroll
        for (int rep = 0; rep < 8; ++rep) {
            int kk = lk + rep * 4;
            float mk = mask[b * NN + kt + kk] * -1e-4f;
            float v = db[(size_t)(kt + kk) * NN + i0 + li];
            At[kk][li] = (mk > 0.5f) ? 0.f : v;
            Xl[kk][li] = xb[(size_t)(kt + kk) * DD + c0 + li];
        }
        __syncthreads();
        for (int kk = 0; kk < 32; ++kk) {
            float av[4], bv[4];
#pragma unroll
            for (int u = 0; u < 4; ++u) { av[u] = At[kk][ty * 4 + u]; bv[u] = Xl[kk][tx * 4 + u]; }
#pragma unroll
            for (int u = 0; u < 4; ++u)
#pragma unroll
                for (int v = 0; v < 4; ++v) acc[u][v] += av[u] * bv[v];
        }
        __syncthreads();
    }
    float* cb = ctx + (size_t)b * NN * DD;
#pragma unroll
    for (int u = 0; u < 4; ++u)
#pragma unroll
        for (int v = 0; v < 4; ++v)
            cb[(size_t)(i0 + ty * 4 + u) * DD + c0 + tx * 4 + v] = acc[u][v];
}

// ---------------- drivers ----------------
template <typename T>
static void run_old(const float* x, const float* adj, const float* mask,
                    const float* rlab, const int* rmask, const float* w, const float* br,
                    float* ctx, float* dmat, float* lossout,
                    char* ws, hipStream_t stream) {
    size_t off = 0;
    T* M  = (T*)(ws + off); off += (size_t)BB * NN * NN * sizeof(T);
    T* Cb = (T*)(ws + off); off += (size_t)BB * NN * KB * sizeof(T);
    T* Bb = (T*)(ws + off); off += (size_t)BB * KB * KB * sizeof(T);
    double* Lp = (double*)(ws + off); off += (size_t)BB * 4 * NN * 8;
    float* Rf  = (float*)(ws + off);  off += (size_t)BB * NN * 4;
    double* Dg = (double*)(ws + off); off += (size_t)BB * NN * 8;
    float* lossp = (float*)(ws + off);

    k_root<<<BB * NN / 4, 256, 0, stream>>>(x, mask, w, br, Rf);
    k_colsum<<<dim3(BB, 4), 512, 0, stream>>>(adj, mask, Lp);
    k_build<T><<<BB * NN, 512, 0, stream>>>(adj, mask, Rf, Lp, M);
    for (int s = 0; s < NSTEP; ++s) {
        int k0 = s * KB;
        k_savecol<T><<<BB * NN / 4, 256, 0, stream>>>(M, Cb, k0);
        k_invblk<T><<<BB, 256, 0, stream>>>(M, Bb, k0);
        k_pivrows<T><<<dim3(BB, 8), 256, 0, stream>>>(M, Bb, k0);
        k_update<T><<<dim3(BB, 8, 8), 256, 0, stream>>>(M, Cb, k0);
    }
    k_dgloss<T><<<BB * NN / 256, 256, 0, stream>>>(M, Rf, rlab, rmask, Dg, lossp);
    k_lossfin<<<1, 128, 0, stream>>>(lossp, lossout);
    k_d<T><<<dim3(BB, 8, 8), 256, 0, stream>>>(M, Dg, adj, mask, dmat);
    k_ctx<<<dim3(BB, 8, 12), 256, 0, stream>>>(dmat, x, mask, ctx);
}

static void run_new(const float* x, const float* adj, const float* mask,
                    const float* rlab, const int* rmask, const float* w, const float* br,
                    float* ctx, float* dmat, float* lossout,
                    char* ws, hipStream_t stream) {
    size_t off = 0;
    double* M  = (double*)(ws + off); off += (size_t)BB * NN * NN * 8;
    double* Cb = (double*)(ws + off); off += (size_t)BB * NN * KB * 8;   // layout only
    double* Bb = (double*)(ws + off); off += (size_t)BB * KB * KB * 8;
    double* Lp = (double*)(ws + off); off += (size_t)BB * 4 * NN * 8;
    float* Rf  = (float*)(ws + off);  off += (size_t)BB * NN * 4;
    double* Dg = (double*)(ws + off); off += (size_t)BB * NN * 8;
    float* lossp = (float*)(ws + off); off += 4096;
    unsigned short* ATh = (unsigned short*)(ws + off); off += (size_t)BB * NN * NN * 2;
    unsigned short* ATl = (unsigned short*)(ws + off); off += (size_t)BB * NN * NN * 2;
    unsigned short* XTh = (unsigned short*)(ws);
    unsigned short* XTl = (unsigned short*)(ws + (size_t)BB * DD * NN * 2);
    (void)Cb;

    k_root<<<BB * NN / 4, 256, 0, stream>>>(x, mask, w, br, Rf);
    k_colsum<<<dim3(BB, 4), 512, 0, stream>>>(adj, mask, Lp);
    k_build<double><<<BB * NN, 512, 0, stream>>>(adj, mask, Rf, Lp, M);
    for (int s = 0; s < NSTEP; ++s) {
        k_piv2<<<dim3(8, BB), 256, 0, stream>>>(M, Bb, s);
        k_upd2<<<dim3(14, BB), 256, 0, stream>>>(M, Bb, s);
    }
    k_dgloss<double><<<BB * NN / 256, 256, 0, stream>>>(M, Rf, rlab, rmask, Dg, lossp);
    k_lossfin<<<1, 128, 0, stream>>>(lossp, lossout);
    k_d2<double><<<dim3(BB, 8, 8), 256, 0, stream>>>(M, Dg, adj, mask, dmat, ATh, ATl);
    k_cvt_x<<<dim3(BB, 8, 12), 256, 0, stream>>>(x, XTh, XTl);   // overwrites M region
    k_ctx4<<<dim3(6, 4, BB), 256, 0, stream>>>(ATh, ATl, XTh, XTl, ctx);
}

extern "C" void kernel_launch(void* const* d_in, const int* in_sizes, int n_in,
                              void* d_out, int out_size, void* d_ws, size_t ws_size,
                              hipStream_t stream) {
    const float* x    = (const float*)d_in[0];
    const float* adj  = (const float*)d_in[1];
    const float* mask = (const float*)d_in[2];
    const float* rlab = (const float*)d_in[3];
    const int*   rmask= (const int*)d_in[4];
    const float* w    = (const float*)d_in[5];
    const float* br   = (const float*)d_in[6];
    float* out = (float*)d_out;
    float* ctx = out;
    float* dmat = out + (size_t)BB * NN * DD;
    float* lossout = dmat + (size_t)BB * NN * NN;
    char* ws = (char*)d_ws;

    size_t base = (size_t)BB * NN * NN * 8 + (size_t)BB * NN * KB * 8 + (size_t)BB * KB * KB * 8
                + (size_t)BB * 4 * NN * 8 + (size_t)BB * NN * 4 + (size_t)BB * NN * 8 + 4096;
    size_t need_new = base + (size_t)BB * NN * NN * 4;
    if (ws_size >= need_new)
        run_new(x, adj, mask, rlab, rmask, w, br, ctx, dmat, lossout, ws, stream);
    else if (ws_size >= base)
        run_old<double>(x, adj, mask, rlab, rmask, w, br, ctx, dmat, lossout, ws, stream);
    else
        run_old<float>(x, adj, mask, rlab, rmask, w, br, ctx, dmat, lossout, ws, stream);
}

// Round 9
// 1177.050 us; speedup vs baseline: 1.1756x; 1.1756x over previous
//
#include <hip/hip_runtime.h>
#include <cstdint>
#include <cstddef>

#define BB 64
#define NN 512
#define DD 768
#define KB 64
#define NSTEP (NN/KB)

typedef __bf16 bf16x8 __attribute__((ext_vector_type(8)));
typedef float f32x4 __attribute__((ext_vector_type(4)));
typedef unsigned short us8 __attribute__((ext_vector_type(8)));
typedef double f64x4 __attribute__((ext_vector_type(4)));
typedef double f64x2 __attribute__((ext_vector_type(2)));

__device__ __forceinline__ float aval(float adjv, float mi, float mj) {
    return expf(fmaxf(adjv - 50.f * (mi + mj), -40.f));
}

__device__ __forceinline__ unsigned short f2bf(float v) {
    union { float f; unsigned int u; } c; c.f = v;
    return (unsigned short)((c.u + 0x7fffu + ((c.u >> 16) & 1u)) >> 16);
}
__device__ __forceinline__ float bf2f(unsigned short h) {
    union { unsigned int u; float f; } c; c.u = ((unsigned int)h) << 16;
    return c.f;
}

__device__ __forceinline__ void gl_lds16(const void* g, void* l) {
    __builtin_amdgcn_global_load_lds((const __attribute__((address_space(1))) unsigned int*)g,
                                     (__attribute__((address_space(3))) unsigned int*)l, 16, 0, 0);
}

// ---------------- root / R ----------------
__global__ void k_root(const float* __restrict__ x, const float* __restrict__ mask,
                       const float* __restrict__ w, const float* __restrict__ br,
                       float* __restrict__ R) {
    int wave = threadIdx.x >> 6, lane = threadIdx.x & 63;
    int row = blockIdx.x * 4 + wave;
    const float* xr = x + (size_t)row * DD;
    float s = 0.f;
#pragma unroll
    for (int k = 0; k < DD / 64; ++k) s += xr[k * 64 + lane] * w[k * 64 + lane];
    for (int off = 32; off; off >>= 1) s += __shfl_down(s, off, 64);
    if (lane == 0) {
        float m = mask[row] * -1e-4f;
        float rv = fmaxf(s + br[0] - 50.f * m, -40.f);
        R[row] = expf(rv);
    }
}

// ---------------- column sums of A (partials) ----------------
__global__ void k_colsum(const float* __restrict__ adj, const float* __restrict__ mask,
                         double* __restrict__ Lp) {
    int b = blockIdx.x, chunk = blockIdx.y;
    int j = threadIdx.x;
    float mj = mask[b * NN + j] * -1e-4f;
    const float* ab = adj + (size_t)b * NN * NN;
    double acc = 0.0;
    int i0 = chunk * 128;
    for (int i = i0; i < i0 + 128; ++i) {
        float mi = mask[b * NN + i] * -1e-4f;
        acc += (double)aval(ab[(size_t)i * NN + j], mi, mj);
    }
    Lp[((size_t)b * 4 + chunk) * NN + j] = acc;
}

// ---------------- build LL ----------------
template <typename T>
__global__ void k_build(const float* __restrict__ adj, const float* __restrict__ mask,
                        const float* __restrict__ R, const double* __restrict__ Lp,
                        T* __restrict__ M) {
    int b = blockIdx.x >> 9;
    int r = blockIdx.x & 511;
    int c = threadIdx.x;
    float mr = mask[b * NN + r] * -1e-4f;
    float mc = mask[b * NN + c] * -1e-4f;
    size_t idx = ((size_t)b * NN + r) * NN + c;
    float a = aval(adj[idx], mr, mc);
    T v;
    if (r == c) {
        const double* lp = Lp + (size_t)b * 4 * NN;
        double L = lp[c] + lp[NN + c] + lp[2 * NN + c] + lp[3 * NN + c];
        v = (T)(L - (double)a + (double)R[b * NN + c]);
    } else {
        v = (T)(-a);
    }
    M[idx] = v;
}

// ---------------- save column panel (fallback path only) ----------------
template <typename T>
__global__ void k_savecol(const T* __restrict__ M, T* __restrict__ Cb, int k0) {
    int t = threadIdx.x;
    int c = t & 63, rr = t >> 6;
    int row = blockIdx.x * 4 + rr;
    int b = row >> 9, i = row & 511;
    Cb[(size_t)row * KB + c] = M[((size_t)b * NN + i) * NN + k0 + c];
}

// ---------------- invert 64x64 pivot block ----------------
template <typename T>
__global__ void k_invblk(const T* __restrict__ M, T* __restrict__ Bb, int k0) {
    __shared__ double pr[KB];
    __shared__ double fv[KB];
    __shared__ double pvt;
    int b = blockIdx.x;
    int r = threadIdx.x & 63, q = threadIdx.x >> 6;
    double a[16];
    const T* Mb = M + ((size_t)b * NN + k0) * NN + k0;
#pragma unroll
    for (int c = 0; c < 16; ++c) a[c] = (double)Mb[(size_t)r * NN + q * 16 + c];
    for (int k = 0; k < KB; ++k) {
        int kq = k >> 4, kc = k & 15;
        if (r == k && q == kq) pvt = a[kc];
        __syncthreads();
        double ip = 1.0 / pvt;
        if (r == k) {
#pragma unroll
            for (int c = 0; c < 16; ++c) a[c] *= ip;
            if (q == kq) a[kc] = ip;
#pragma unroll
            for (int c = 0; c < 16; ++c) pr[q * 16 + c] = a[c];
        }
        if (r != k && q == kq) fv[r] = a[kc];
        __syncthreads();
        if (r != k) {
            double f = fv[r];
#pragma unroll
            for (int c = 0; c < 16; ++c) a[c] -= f * pr[q * 16 + c];
            if (q == kq) a[kc] = -f * ip;
        }
        __syncthreads();
    }
    T* Bo = Bb + (size_t)b * KB * KB;
#pragma unroll
    for (int c = 0; c < 16; ++c) Bo[r * KB + q * 16 + c] = (T)a[c];
}

// ---------------- MFMA pivot rows: M[step rows, jt] = Binv @ Mold ----------------
// f64 16x16x4 C/D map (HW-verified r4/r5): row = (lane>>4) + 4*reg, col = lane&15
// 1D grid 512 with XCD-chunk swizzle: each XCD gets 8 whole batches.
__global__ __launch_bounds__(256) void k_piv_mfma(double* __restrict__ M,
                                                  const double* __restrict__ Bb, int step) {
    __shared__ double Ms[64][66];
    int o = blockIdx.x;
    int g = (o & 7) * 64 + (o >> 3);
    int b = g >> 3, jt = g & 7;
    int t = threadIdx.x, w = t >> 6, l = t & 63;
    double* Mb = M + (size_t)b * NN * NN;
    double* Pr = Mb + (size_t)(step * 64) * NN;
    const double* Bi = Bb + (size_t)b * KB * KB;
    if (jt == step) {
        for (int i = 0; i < 16; ++i) {
            int c = i * 256 + t;
            int row = c >> 6, col = c & 63;
            Pr[(size_t)row * NN + step * 64 + col] = Bi[row * 64 + col];
        }
        return;
    }
    const double* Mg = Pr + jt * 64;
    for (int i = 0; i < 8; ++i) {
        int c = i * 256 + t;
        int row = c >> 5, ch = c & 31;
        f64x2 v = *(const f64x2*)(Mg + (size_t)row * NN + ch * 2);
        Ms[row][ch * 2] = v[0]; Ms[row][ch * 2 + 1] = v[1];
    }
    __syncthreads();
    int lr = l & 15, lg = l >> 4;
    double a[16];
#pragma unroll
    for (int kk = 0; kk < 16; ++kk) a[kk] = Bi[(w * 16 + lr) * 64 + kk * 4 + lg];
    double* Og = Pr + (size_t)(w * 16) * NN + jt * 64;
#pragma unroll
    for (int cf = 0; cf < 4; ++cf) {
        f64x4 acc = {0., 0., 0., 0.};
#pragma unroll
        for (int kk = 0; kk < 16; ++kk)
            acc = __builtin_amdgcn_mfma_f64_16x16x4f64(a[kk], Ms[kk * 4 + lg][cf * 16 + lr], acc, 0, 0, 0);
#pragma unroll
        for (int r = 0; r < 4; ++r) Og[(size_t)(lg + 4 * r) * NN + cf * 16 + lr] = acc[r];
    }
}

// ---------------- fused MFMA rank-64 update (upd0 + upd1) ----------------
// 1D grid 896 with XCD-chunk swizzle: each XCD gets 8 batches x 14 blocks,
// so the R(step,jt) panels are shared within one XCD's L2.
__global__ __launch_bounds__(256) void k_upd2(double* __restrict__ M,
                                              const double* __restrict__ Bb, int step) {
    __shared__ double Ts[64][66];
    int o = blockIdx.x;
    int g = (o & 7) * 112 + (o >> 3);
    int b = g / 14;
    int x = g % 14;
    int it = x >> 1, half = x & 1;
    if (it >= step) ++it;
    int t = threadIdx.x, w = t >> 6, l = t & 63;
    double* Mb = M + (size_t)b * NN * NN;
    {
        const double* Cg = Mb + (size_t)(it * 64) * NN + step * 64;
        for (int i = 0; i < 8; ++i) {
            int c = i * 256 + t;
            int row = c >> 5, ch = c & 31;
            f64x2 v = *(const f64x2*)(Cg + (size_t)row * NN + ch * 2);
            Ts[row][ch * 2] = -v[0]; Ts[row][ch * 2 + 1] = -v[1];
        }
    }
    __syncthreads();
    int lr = l & 15, lg = l >> 4;
    double a[16];
#pragma unroll
    for (int kk = 0; kk < 16; ++kk) a[kk] = Ts[w * 16 + lr][kk * 4 + lg];
    __syncthreads();
    int nj = half ? 3 : 4;
    for (int jj = 0; jj < nj; ++jj) {
        int jtidx = half ? 4 + jj : jj;
        int jt = (jtidx < step) ? jtidx : jtidx + 1;
        const double* Rg = Mb + (size_t)(step * 64) * NN + jt * 64;
        for (int i = 0; i < 8; ++i) {
            int c = i * 256 + t;
            int row = c >> 5, ch = c & 31;
            f64x2 v = *(const f64x2*)(Rg + (size_t)row * NN + ch * 2);
            Ts[row][ch * 2] = v[0]; Ts[row][ch * 2 + 1] = v[1];
        }
        __syncthreads();
        double* Og = Mb + (size_t)(it * 64 + w * 16) * NN + jt * 64;
#pragma unroll
        for (int cf = 0; cf < 4; ++cf) {
            int c0 = cf * 16 + lr;
            f64x4 acc;
#pragma unroll
            for (int r = 0; r < 4; ++r) acc[r] = Og[(size_t)(lg + 4 * r) * NN + c0];
#pragma unroll
            for (int kk = 0; kk < 16; ++kk)
                acc = __builtin_amdgcn_mfma_f64_16x16x4f64(a[kk], Ts[kk * 4 + lg][c0], acc, 0, 0, 0);
#pragma unroll
            for (int r = 0; r < 4; ++r) Og[(size_t)(lg + 4 * r) * NN + c0] = acc[r];
        }
        __syncthreads();
    }
    if (half) {
        const double* Bi = Bb + (size_t)b * KB * KB;
        for (int i = 0; i < 8; ++i) {
            int c = i * 256 + t;
            int row = c >> 5, ch = c & 31;
            f64x2 v = *(const f64x2*)(Bi + row * 64 + ch * 2);
            Ts[row][ch * 2] = v[0]; Ts[row][ch * 2 + 1] = v[1];
        }
        __syncthreads();
        double* Og = Mb + (size_t)(it * 64 + w * 16) * NN + step * 64;
#pragma unroll
        for (int cf = 0; cf < 4; ++cf) {
            int c0 = cf * 16 + lr;
            f64x4 acc = {0., 0., 0., 0.};
#pragma unroll
            for (int kk = 0; kk < 16; ++kk)
                acc = __builtin_amdgcn_mfma_f64_16x16x4f64(a[kk], Ts[kk * 4 + lg][c0], acc, 0, 0, 0);
#pragma unroll
            for (int r = 0; r < 4; ++r) Og[(size_t)(lg + 4 * r) * NN + c0] = acc[r];
        }
    }
}

// ---------------- scalar pivrows / update (fallback path only) ----------------
template <typename T>
__global__ void k_pivrows(T* __restrict__ M, const T* __restrict__ Bb, int k0) {
    __shared__ double Bi[KB][KB];
    __shared__ double Mt[KB][KB + 1];
    int b = blockIdx.x, jt = blockIdx.y * 64;
    const T* Bo = Bb + (size_t)b * KB * KB;
    T* Mb = M + ((size_t)b * NN + k0) * NN;
    int t = threadIdx.x;
    for (int e = t; e < KB * KB; e += 256) {
        int rr = e >> 6, cc = e & 63;
        Bi[rr][cc] = (double)Bo[e];
        Mt[rr][cc] = (double)Mb[(size_t)rr * NN + jt + cc];
    }
    __syncthreads();
    if (blockIdx.y == (unsigned)(k0 >> 6)) {
        for (int e = t; e < KB * KB; e += 256) {
            int rr = e >> 6, cc = e & 63;
            Mb[(size_t)rr * NN + jt + cc] = (T)Bi[rr][cc];
        }
        return;
    }
    int tx = t & 15, ty = t >> 4;
    double acc[4][4] = {};
    for (int k = 0; k < KB; ++k) {
        double av[4], bv[4];
#pragma unroll
        for (int u = 0; u < 4; ++u) { av[u] = Bi[ty * 4 + u][k]; bv[u] = Mt[k][tx * 4 + u]; }
#pragma unroll
        for (int u = 0; u < 4; ++u)
#pragma unroll
            for (int v = 0; v < 4; ++v) acc[u][v] += av[u] * bv[v];
    }
#pragma unroll
    for (int u = 0; u < 4; ++u)
#pragma unroll
        for (int v = 0; v < 4; ++v)
            Mb[(size_t)(ty * 4 + u) * NN + jt + tx * 4 + v] = (T)acc[u][v];
}

template <typename T>
__global__ void k_update(T* __restrict__ M, const T* __restrict__ Cb, int k0) {
    int step = k0 >> 6;
    int it = blockIdx.y;
    if (it == step) return;
    int b = blockIdx.x, jt = blockIdx.z;
    __shared__ double Ct[KB][KB + 1];
    __shared__ double Rt[KB][KB + 1];
    int t = threadIdx.x;
    const T* Cbb = Cb + ((size_t)b * NN + it * 64) * KB;
    const T* Rb  = M + ((size_t)b * NN + k0) * NN + jt * 64;
    for (int e = t; e < KB * KB; e += 256) {
        int rr = e >> 6, cc = e & 63;
        Ct[rr][cc] = (double)Cbb[(size_t)rr * KB + cc];
        Rt[rr][cc] = (double)Rb[(size_t)rr * NN + cc];
    }
    __syncthreads();
    int tx = t & 15, ty = t >> 4;
    double acc[4][4] = {};
    for (int k = 0; k < KB; ++k) {
        double av[4], bv[4];
#pragma unroll
        for (int u = 0; u < 4; ++u) { av[u] = Ct[ty * 4 + u][k]; bv[u] = Rt[k][tx * 4 + u]; }
#pragma unroll
        for (int u = 0; u < 4; ++u)
#pragma unroll
            for (int v = 0; v < 4; ++v) acc[u][v] += av[u] * bv[v];
    }
    T* Mo = M + ((size_t)b * NN + it * 64) * NN + jt * 64;
    bool blockcol = (jt == step);
#pragma unroll
    for (int u = 0; u < 4; ++u) {
        int row = ty * 4 + u;
#pragma unroll
        for (int v = 0; v < 4; ++v) {
            int col = tx * 4 + v;
            double val = (double)Mo[(size_t)row * NN + col] - acc[u][v];
            if (blockcol) val -= Ct[row][col];
            Mo[(size_t)row * NN + col] = (T)val;
        }
    }
}

// ---------------- diag extraction + BCE loss ----------------
template <typename T>
__global__ void k_dgloss(const T* __restrict__ M, const float* __restrict__ R,
                         const float* __restrict__ rlab, const int* __restrict__ rmask,
                         double* __restrict__ Dg, float* __restrict__ lossp) {
    int idx = blockIdx.x * 256 + threadIdx.x;
    int b = idx >> 9, n = idx & 511;
    double xv = (double)M[((size_t)b * NN + n) * NN + n];
    Dg[idx] = xv;
    float d0 = R[idx] * (float)xv;
    float lg = fminf(fmaxf(d0, 1e-5f), 1.f - 1e-5f);
    float rm = (float)rmask[idx];
    float lab = (rmask[idx] == 1) ? rlab[idx] : 0.f;
    float bce = -(lab * logf(lg) + (1.f - lab) * logf(1.f - lg));
    __shared__ double sm[256];
    sm[threadIdx.x] = (double)(bce * rm);
    __syncthreads();
    for (int s = 128; s; s >>= 1) {
        if (threadIdx.x < s) sm[threadIdx.x] += sm[threadIdx.x + s];
        __syncthreads();
    }
    if (threadIdx.x == 0) lossp[blockIdx.x] = (float)sm[0];
}

__global__ void k_lossfin(const float* __restrict__ lossp, float* __restrict__ outv) {
    __shared__ double sm[128];
    sm[threadIdx.x] = (double)lossp[threadIdx.x];
    __syncthreads();
    for (int s = 64; s; s >>= 1) {
        if (threadIdx.x < s) sm[threadIdx.x] += sm[threadIdx.x + s];
        __syncthreads();
    }
    if (threadIdx.x == 0) outv[0] = (float)(sm[0] / (double)(BB * NN));
}

// ---------------- d (fallback path) ----------------
template <typename T>
__global__ void k_d(const T* __restrict__ M, const double* __restrict__ Dg,
                    const float* __restrict__ adj, const float* __restrict__ mask,
                    float* __restrict__ dout) {
    int b = blockIdx.x, i0 = blockIdx.y * 64, j0 = blockIdx.z * 64;
    __shared__ double Xt[64][65];
    int t = threadIdx.x, ii = t & 63, jj0 = t >> 6;
    const T* Mb = M + (size_t)b * NN * NN;
    for (int jj = jj0; jj < 64; jj += 4)
        Xt[jj][ii] = (double)Mb[(size_t)(j0 + jj) * NN + i0 + ii];
    __syncthreads();
    int jc = t & 63, ir0 = t >> 6;
    float mj = mask[b * NN + j0 + jc] * -1e-4f;
    double dg = Dg[b * NN + j0 + jc];
    const float* ab = adj + (size_t)b * NN * NN;
    float* db = dout + (size_t)b * NN * NN;
    for (int ir = ir0; ir < 64; ir += 4) {
        int i = i0 + ir;
        float mi = mask[b * NN + i] * -1e-4f;
        float a = aval(ab[(size_t)i * NN + j0 + jc], mi, mj);
        db[(size_t)i * NN + j0 + jc] = a * (float)(dg - Xt[jc][ir]);
    }
}

// ---------------- d + transposed masked bf16 hi/lo attn (f32 X staging) ----------------
template <typename T>
__global__ void k_d2(const T* __restrict__ M, const double* __restrict__ Dg,
                     const float* __restrict__ adj, const float* __restrict__ mask,
                     float* __restrict__ dout,
                     unsigned short* __restrict__ ATh, unsigned short* __restrict__ ATl) {
    int b = blockIdx.x, i0 = blockIdx.y * 64, j0 = blockIdx.z * 64;
    __shared__ float Xt[64][65];
    __shared__ float dt[64][65];
    int t = threadIdx.x, ii = t & 63, jj0 = t >> 6;
    const T* Mb = M + (size_t)b * NN * NN;
    for (int jj = jj0; jj < 64; jj += 4)
        Xt[jj][ii] = (float)Mb[(size_t)(j0 + jj) * NN + i0 + ii];
    __syncthreads();
    int jc = t & 63, ir0 = t >> 6;
    float mj = mask[b * NN + j0 + jc] * -1e-4f;
    double dg = Dg[b * NN + j0 + jc];
    const float* ab = adj + (size_t)b * NN * NN;
    float* db = dout + (size_t)b * NN * NN;
    for (int ir = ir0; ir < 64; ir += 4) {
        int i = i0 + ir;
        float mi = mask[b * NN + i] * -1e-4f;
        float a = aval(ab[(size_t)i * NN + j0 + jc], mi, mj);
        float v = a * (float)(dg - (double)Xt[jc][ir]);
        db[(size_t)i * NN + j0 + jc] = v;
        dt[ir][jc] = v;
    }
    __syncthreads();
    int ql = t >> 2, kq = t & 3;
    us8 vh0, vh1, vl0, vl1;
#pragma unroll
    for (int u = 0; u < 16; ++u) {
        int k = kq * 16 + u;
        float mk = mask[b * NN + i0 + k] * -1e-4f;
        float v = (mk > 0.5f) ? 0.f : dt[k][ql];
        unsigned short h = f2bf(v);
        unsigned short lo = f2bf(v - bf2f(h));
        if (u < 8) { vh0[u] = h; vl0[u] = lo; } else { vh1[u - 8] = h; vl1[u - 8] = lo; }
    }
    size_t ao = ((size_t)b * NN + j0 + ql) * NN + i0 + kq * 16;
    *(us8*)&ATh[ao] = vh0; *(us8*)&ATh[ao + 8] = vh1;
    *(us8*)&ATl[ao] = vl0; *(us8*)&ATl[ao + 8] = vl1;
}

// ---------------- x -> transposed bf16 hi/lo ----------------
__global__ void k_cvt_x(const float* __restrict__ x,
                        unsigned short* __restrict__ XTh, unsigned short* __restrict__ XTl) {
    int b = blockIdx.x, k0 = blockIdx.y * 64, c0 = blockIdx.z * 64;
    __shared__ float xs[64][65];
    int t = threadIdx.x;
#pragma unroll
    for (int rep = 0; rep < 16; ++rep) {
        int e = rep * 256 + t;
        int row = e >> 6, col = e & 63;
        xs[row][col] = x[((size_t)b * NN + k0 + row) * DD + c0 + col];
    }
    __syncthreads();
    int cl = t >> 2, kq = t & 3;
    us8 vh0, vh1, vl0, vl1;
#pragma unroll
    for (int u = 0; u < 16; ++u) {
        int k = kq * 16 + u;
        float v = xs[k][cl];
        unsigned short h = f2bf(v);
        unsigned short lo = f2bf(v - bf2f(h));
        if (u < 8) { vh0[u] = h; vl0[u] = lo; } else { vh1[u - 8] = h; vl1[u - 8] = lo; }
    }
    size_t ao = ((size_t)b * DD + c0 + cl) * NN + k0 + kq * 16;
    *(us8*)&XTh[ao] = vh0; *(us8*)&XTh[ao + 8] = vh1;
    *(us8*)&XTl[ao] = vl0; *(us8*)&XTl[ao + 8] = vl1;
}

// ---------------- context GEMM: double-buffered + XCD-chunk swizzle ----------------
// 1536 blocks; g = (o&7)*192 + (o>>3): each XCD owns 8 whole batches (2.5 MB
// working set < 4 MB per-XCD L2) => A/X panels shared within one XCD.
__global__ __launch_bounds__(256) void k_ctx5(const unsigned short* __restrict__ ATh,
                                              const unsigned short* __restrict__ ATl,
                                              const unsigned short* __restrict__ XTh,
                                              const unsigned short* __restrict__ XTl,
                                              float* __restrict__ ctx) {
    __shared__ __align__(16) unsigned short ABs[2][128 * 64];
    __shared__ __align__(16) unsigned short Xs[2][128 * 64];
    int o = blockIdx.x;
    int g = (o & 7) * 192 + (o >> 3);
    int b = g / 24;
    int rem = g % 24;
    int bm = (rem / 6) * 128, bn = (rem % 6) * 128;
    int t = threadIdx.x, wid = t >> 6, lane = t & 63;
    f32x4 acc[4][4];
#pragma unroll
    for (int i = 0; i < 4; ++i)
#pragma unroll
        for (int j = 0; j < 4; ++j) acc[i][j] = (f32x4){0.f, 0.f, 0.f, 0.f};

    const unsigned short* Agh = ATh + ((size_t)b * NN + bm) * NN;
    const unsigned short* Agl = ATl + ((size_t)b * NN + bm) * NN;
    const unsigned short* Xgh = XTh + ((size_t)b * DD + bn) * NN;
    const unsigned short* Xgl = XTl + ((size_t)b * DD + bn) * NN;

    int m0 = (wid >> 1) * 64, n0 = (wid & 1) * 64;
    int kc = lane >> 4;

    auto STAGE = [&](int kt, int buf) {
        int ki = kt * 32;
#pragma unroll
        for (int it2 = 0; it2 < 4; ++it2) {
            int chunk = it2 * 256 + wid * 64 + lane;
            int row = chunk >> 3;
            int gs = (chunk & 7) ^ (row & 7);
            const unsigned short* s = (gs < 4) ? Agh + (size_t)row * NN + ki + gs * 8
                                               : Agl + (size_t)row * NN + ki + (gs - 4) * 8;
            gl_lds16(s, &ABs[buf][(it2 * 256 + wid * 64) * 8]);
        }
#pragma unroll
        for (int it2 = 0; it2 < 4; ++it2) {
            int chunk = it2 * 256 + wid * 64 + lane;
            int row = chunk >> 3;
            int gs = (chunk & 7) ^ (row & 7);
            const unsigned short* s = (gs < 4) ? Xgh + (size_t)row * NN + ki + gs * 8
                                               : Xgl + (size_t)row * NN + ki + (gs - 4) * 8;
            gl_lds16(s, &Xs[buf][(it2 * 256 + wid * 64) * 8]);
        }
    };

    STAGE(0, 0);
    int cur = 0;
    for (int kt = 0; kt < 16; ++kt) {
        if (kt + 1 < 16) {
            STAGE(kt + 1, cur ^ 1);
            asm volatile("s_waitcnt vmcnt(8)" ::: "memory");
        } else {
            asm volatile("s_waitcnt vmcnt(0)" ::: "memory");
        }
        __builtin_amdgcn_s_barrier();
        bf16x8 ah[4], al[4], xh[4], xl[4];
#pragma unroll
        for (int f = 0; f < 4; ++f) {
            int ar = m0 + f * 16 + (lane & 15);
            ah[f] = *(const bf16x8*)&ABs[cur][(ar * 8 + (kc ^ (ar & 7))) * 8];
            al[f] = *(const bf16x8*)&ABs[cur][(ar * 8 + ((kc | 4) ^ (ar & 7))) * 8];
            int br = n0 + f * 16 + (lane & 15);
            xh[f] = *(const bf16x8*)&Xs[cur][(br * 8 + (kc ^ (br & 7))) * 8];
            xl[f] = *(const bf16x8*)&Xs[cur][(br * 8 + ((kc | 4) ^ (br & 7))) * 8];
        }
#pragma unroll
        for (int fm = 0; fm < 4; ++fm)
#pragma unroll
            for (int fn = 0; fn < 4; ++fn) {
                acc[fm][fn] = __builtin_amdgcn_mfma_f32_16x16x32_bf16(ah[fm], xh[fn], acc[fm][fn], 0, 0, 0);
                acc[fm][fn] = __builtin_amdgcn_mfma_f32_16x16x32_bf16(ah[fm], xl[fn], acc[fm][fn], 0, 0, 0);
                acc[fm][fn] = __builtin_amdgcn_mfma_f32_16x16x32_bf16(al[fm], xh[fn], acc[fm][fn], 0, 0, 0);
            }
        __builtin_amdgcn_s_barrier();
        cur ^= 1;
    }
    float* cb = ctx + ((size_t)b * NN + bm + m0) * DD + bn + n0;
#pragma unroll
    for (int fm = 0; fm < 4; ++fm)
#pragma unroll
        for (int fn = 0; fn < 4; ++fn)
#pragma unroll
            for (int r = 0; r < 4; ++r) {
                int row = fm * 16 + (lane >> 4) * 4 + r;
                int col = fn * 16 + (lane & 15);
                cb[(size_t)row * DD + col] = acc[fm][fn][r];
            }
}

// ---------------- context (fallback) ----------------
__global__ void k_ctx(const float* __restrict__ dmat, const float* __restrict__ x,
                      const float* __restrict__ mask, float* __restrict__ ctx) {
    int b = blockIdx.x, i0 = blockIdx.y * 64, c0 = blockIdx.z * 64;
    __shared__ float At[32][65];
    __shared__ float Xl[32][65];
    int t = threadIdx.x;
    int tx = t & 15, ty = t >> 4;
    float acc[4][4] = {};
    const float* db = dmat + (size_t)b * NN * NN;
    const float* xb = x + (size_t)b * NN * DD;
    int li = t & 63, lk = t >> 6;
    for (int kt = 0; kt < NN; kt += 32) {
#pragma unroll
        for (int rep = 0; rep < 8; ++rep) {
            int kk = lk + rep * 4;
            float mk = mask[b * NN + kt + kk] * -1e-4f;
            float v = db[(size_t)(kt + kk) * NN + i0 + li];
            At[kk][li] = (mk > 0.5f) ? 0.f : v;
            Xl[kk][li] = xb[(size_t)(kt + kk) * DD + c0 + li];
        }
        __syncthreads();
        for (int kk = 0; kk < 32; ++kk) {
            float av[4], bv[4];
#pragma unroll
            for (int u = 0; u < 4; ++u) { av[u] = At[kk][ty * 4 + u]; bv[u] = Xl[kk][tx * 4 + u]; }
#pragma unroll
            for (int u = 0; u < 4; ++u)
#pragma unroll
                for (int v = 0; v < 4; ++v) acc[u][v] += av[u] * bv[v];
        }
        __syncthreads();
    }
    float* cb = ctx + (size_t)b * NN * DD;
#pragma unroll
    for (int u = 0; u < 4; ++u)
#pragma unroll
        for (int v = 0; v < 4; ++v)
            cb[(size_t)(i0 + ty * 4 + u) * DD + c0 + tx * 4 + v] = acc[u][v];
}

// ---------------- drivers ----------------
template <typename T>
static void run_old(const float* x, const float* adj, const float* mask,
                    const float* rlab, const int* rmask, const float* w, const float* br,
                    float* ctx, float* dmat, float* lossout,
                    char* ws, hipStream_t stream) {
    size_t off = 0;
    T* M  = (T*)(ws + off); off += (size_t)BB * NN * NN * sizeof(T);
    T* Cb = (T*)(ws + off); off += (size_t)BB * NN * KB * sizeof(T);
    T* Bb = (T*)(ws + off); off += (size_t)BB * KB * KB * sizeof(T);
    double* Lp = (double*)(ws + off); off += (size_t)BB * 4 * NN * 8;
    float* Rf  = (float*)(ws + off);  off += (size_t)BB * NN * 4;
    double* Dg = (double*)(ws + off); off += (size_t)BB * NN * 8;
    float* lossp = (float*)(ws + off);

    k_root<<<BB * NN / 4, 256, 0, stream>>>(x, mask, w, br, Rf);
    k_colsum<<<dim3(BB, 4), 512, 0, stream>>>(adj, mask, Lp);
    k_build<T><<<BB * NN, 512, 0, stream>>>(adj, mask, Rf, Lp, M);
    for (int s = 0; s < NSTEP; ++s) {
        int k0 = s * KB;
        k_savecol<T><<<BB * NN / 4, 256, 0, stream>>>(M, Cb, k0);
        k_invblk<T><<<BB, 256, 0, stream>>>(M, Bb, k0);
        k_pivrows<T><<<dim3(BB, 8), 256, 0, stream>>>(M, Bb, k0);
        k_update<T><<<dim3(BB, 8, 8), 256, 0, stream>>>(M, Cb, k0);
    }
    k_dgloss<T><<<BB * NN / 256, 256, 0, stream>>>(M, Rf, rlab, rmask, Dg, lossp);
    k_lossfin<<<1, 128, 0, stream>>>(lossp, lossout);
    k_d<T><<<dim3(BB, 8, 8), 256, 0, stream>>>(M, Dg, adj, mask, dmat);
    k_ctx<<<dim3(BB, 8, 12), 256, 0, stream>>>(dmat, x, mask, ctx);
}

static void run_new(const float* x, const float* adj, const float* mask,
                    const float* rlab, const int* rmask, const float* w, const float* br,
                    float* ctx, float* dmat, float* lossout,
                    char* ws, hipStream_t stream) {
    size_t off = 0;
    double* M  = (double*)(ws + off); off += (size_t)BB * NN * NN * 8;
    double* Cb = (double*)(ws + off); off += (size_t)BB * NN * KB * 8;   // layout only
    double* Bb = (double*)(ws + off); off += (size_t)BB * KB * KB * 8;
    double* Lp = (double*)(ws + off); off += (size_t)BB * 4 * NN * 8;
    float* Rf  = (float*)(ws + off);  off += (size_t)BB * NN * 4;
    double* Dg = (double*)(ws + off); off += (size_t)BB * NN * 8;
    float* lossp = (float*)(ws + off); off += 4096;
    unsigned short* ATh = (unsigned short*)(ws + off); off += (size_t)BB * NN * NN * 2;
    unsigned short* ATl = (unsigned short*)(ws + off); off += (size_t)BB * NN * NN * 2;
    unsigned short* XTh = (unsigned short*)(ws);
    unsigned short* XTl = (unsigned short*)(ws + (size_t)BB * DD * NN * 2);
    (void)Cb;

    k_root<<<BB * NN / 4, 256, 0, stream>>>(x, mask, w, br, Rf);
    k_colsum<<<dim3(BB, 4), 512, 0, stream>>>(adj, mask, Lp);
    k_build<double><<<BB * NN, 512, 0, stream>>>(adj, mask, Rf, Lp, M);
    for (int s = 0; s < NSTEP; ++s) {
        k_invblk<double><<<BB, 256, 0, stream>>>(M, Bb, s * KB);
        k_piv_mfma<<<512, 256, 0, stream>>>(M, Bb, s);
        k_upd2<<<896, 256, 0, stream>>>(M, Bb, s);
    }
    k_dgloss<double><<<BB * NN / 256, 256, 0, stream>>>(M, Rf, rlab, rmask, Dg, lossp);
    k_lossfin<<<1, 128, 0, stream>>>(lossp, lossout);
    k_d2<double><<<dim3(BB, 8, 8), 256, 0, stream>>>(M, Dg, adj, mask, dmat, ATh, ATl);
    k_cvt_x<<<dim3(BB, 8, 12), 256, 0, stream>>>(x, XTh, XTl);   // overwrites M region
    k_ctx5<<<1536, 256, 0, stream>>>(ATh, ATl, XTh, XTl, ctx);
}

extern "C" void kernel_launch(void* const* d_in, const int* in_sizes, int n_in,
                              void* d_out, int out_size, void* d_ws, size_t ws_size,
                              hipStream_t stream) {
    const float* x    = (const float*)d_in[0];
    const float* adj  = (const float*)d_in[1];
    const float* mask = (const float*)d_in[2];
    const float* rlab = (const float*)d_in[3];
    const int*   rmask= (const int*)d_in[4];
    const float* w    = (const float*)d_in[5];
    const float* br   = (const float*)d_in[6];
    float* out = (float*)d_out;
    float* ctx = out;
    float* dmat = out + (size_t)BB * NN * DD;
    float* lossout = dmat + (size_t)BB * NN * NN;
    char* ws = (char*)d_ws;

    size_t base = (size_t)BB * NN * NN * 8 + (size_t)BB * NN * KB * 8 + (size_t)BB * KB * KB * 8
                + (size_t)BB * 4 * NN * 8 + (size_t)BB * NN * 4 + (size_t)BB * NN * 8 + 4096;
    size_t need_new = base + (size_t)BB * NN * NN * 4;
    if (ws_size >= need_new)
        run_new(x, adj, mask, rlab, rmask, w, br, ctx, dmat, lossout, ws, stream);
    else if (ws_size >= base)
        run_old<double>(x, adj, mask, rlab, rmask, w, br, ctx, dmat, lossout, ws, stream);
    else
        run_old<float>(x, adj, mask, rlab, rmask, w, br, ctx, dmat, lossout, ws, stream);
}